// Round 3
// baseline (134.273 us; speedup 1.0000x reference)
//
#include <hip/hip_runtime.h>
#include <hip/hip_bf16.h>

#define B_ 4
#define S_ 4096
#define DM 1024
#define H_ 16
#define HD 64
#define BH (B_*H_)
#define SPLIT 16
#define CHUNK (S_/SPLIT)   // 256

typedef __attribute__((ext_vector_type(8))) __bf16 bf16x8;
typedef __attribute__((ext_vector_type(4))) float f32x4;

#define MFMA16(a,b,c) __builtin_amdgcn_mfma_f32_16x16x32_bf16((a),(b),(c),0,0,0)

__device__ __forceinline__ void gload_lds16(const void* g, void* l) {
  __builtin_amdgcn_global_load_lds(
      (const __attribute__((address_space(1))) void*)g,
      (__attribute__((address_space(3))) void*)l, 16, 0, 0);
}

// ---------------------------------------------------------------------------
// K1: partial KV[split][bh][d][e] = sum_{s in chunk} K[s][d] * V[s][e]  (f32)
// grid = SPLIT*BH = 1024 blocks, 256 threads. (unchanged, verified)
// ---------------------------------------------------------------------------
__global__ __launch_bounds__(256)
void k1_kv_partial(const float* __restrict__ Kg,
                   const float* __restrict__ Vg,
                   float* __restrict__ partial) {
  constexpr int LDP = 264;
  __shared__ __align__(16) __bf16 Kt[64 * LDP];
  __shared__ __align__(16) __bf16 Vt[64 * LDP];
  const int bid = blockIdx.x;
  const int split = bid >> 6;
  const int bh = bid & (BH - 1);
  const int b = bh >> 4, h = bh & 15;
  const int s0 = split * CHUNK;
  const int t = threadIdx.x;
  const float* Kbase = Kg + ((size_t)b * S_ + s0) * DM + h * HD;
  const float* Vbase = Vg + ((size_t)b * S_ + s0) * DM + h * HD;
  const int c = t & 15, sr = t >> 4;
  const int d0 = c * 4;
#pragma unroll
  for (int it = 0; it < 16; ++it) {
    const int s = it * 16 + sr;
    f32x4 kv = *reinterpret_cast<const f32x4*>(Kbase + (size_t)s * DM + d0);
    f32x4 vv = *reinterpret_cast<const f32x4*>(Vbase + (size_t)s * DM + d0);
#pragma unroll
    for (int j = 0; j < 4; ++j) {
      Kt[(d0 + j) * LDP + s] = (__bf16)kv[j];
      Vt[(d0 + j) * LDP + s] = (__bf16)vv[j];
    }
  }
  __syncthreads();
  const int w = t >> 6, l = t & 63, lr = l & 15, lg = l >> 4;
  f32x4 acc[4] = {};
#pragma unroll
  for (int ks = 0; ks < 8; ++ks) {
    bf16x8 a = *reinterpret_cast<const bf16x8*>(&Kt[(w * 16 + lr) * LDP + ks * 32 + lg * 8]);
#pragma unroll
    for (int n = 0; n < 4; ++n) {
      bf16x8 bb = *reinterpret_cast<const bf16x8*>(&Vt[(n * 16 + lr) * LDP + ks * 32 + lg * 8]);
      acc[n] = MFMA16(a, bb, acc[n]);
    }
  }
  float* dst = partial + ((size_t)(split * BH + bh) << 12);
#pragma unroll
  for (int n = 0; n < 4; ++n)
#pragma unroll
    for (int r = 0; r < 4; ++r) {
      const int d = w * 16 + lg * 4 + r;
      const int e = n * 16 + lr;
      dst[d * 64 + e] = acc[n][r];
    }
}

// ---------------------------------------------------------------------------
// K2: reduce 16 partials -> kvt[bh][d][e] bf16 (natural layout, no transpose).
// grid = BH*4 = 256 blocks (quartered for occupancy).
// ---------------------------------------------------------------------------
__global__ __launch_bounds__(256)
void k2_kv_reduce(const float* __restrict__ partial,
                  __bf16* __restrict__ kvt) {
  const int bid = blockIdx.x;
  const int bh = bid >> 2, q = bid & 3;
  const int t = threadIdx.x;
#pragma unroll
  for (int i = 0; i < 4; ++i) {
    const int idx = q * 1024 + i * 256 + t;   // d*64+e
    float s = 0.f;
#pragma unroll
    for (int sp = 0; sp < SPLIT; ++sp)
      s += partial[((size_t)(sp * BH + bh) << 12) + idx];
    kvt[((size_t)bh << 12) + idx] = (__bf16)s;
  }
}

// ---------------------------------------------------------------------------
// K2.5: Ut[b][n][h*64+d] = sum_e W[n][h*64+e] * KV[bh][d][e]   (bf16 out)
// grid = BH*4 = 256 blocks (bh = bid>>2, nblk = bid&3), 4 waves.
// A = W rows (f32, converted on the fly), B = kvt rows. Pure-register MFMA.
// ---------------------------------------------------------------------------
__global__ __launch_bounds__(256)
void k25_u(const float* __restrict__ Wg,
           const __bf16* __restrict__ kvt,
           __bf16* __restrict__ Ut) {
  const int bid = blockIdx.x;
  const int bh = bid >> 2, nblk = bid & 3;
  const int b = bh >> 4, h = bh & 15;
  const int t = threadIdx.x, w = t >> 6, l = t & 63, lr = l & 15, lg = l >> 4;
  const int n0w = nblk * 256 + w * 64;
  const __bf16* kvb = kvt + ((size_t)bh << 12);
  f32x4 acc[4][4] = {};
#pragma unroll
  for (int ks = 0; ks < 2; ++ks) {
    bf16x8 bfr[4];
#pragma unroll
    for (int nf = 0; nf < 4; ++nf)
      bfr[nf] = *reinterpret_cast<const bf16x8*>(kvb + (nf * 16 + lr) * 64 + ks * 32 + lg * 8);
#pragma unroll
    for (int mf = 0; mf < 4; ++mf) {
      const int n = n0w + mf * 16 + lr;
      const float* wp = Wg + (size_t)n * DM + h * 64 + ks * 32 + lg * 8;
      f32x4 w0 = *reinterpret_cast<const f32x4*>(wp);
      f32x4 w1 = *reinterpret_cast<const f32x4*>(wp + 4);
      bf16x8 af;
#pragma unroll
      for (int j = 0; j < 4; ++j) { af[j] = (__bf16)w0[j]; af[4 + j] = (__bf16)w1[j]; }
#pragma unroll
      for (int nf = 0; nf < 4; ++nf)
        acc[mf][nf] = MFMA16(af, bfr[nf], acc[mf][nf]);
    }
  }
  __bf16* ub = Ut + ((size_t)b << 20);
#pragma unroll
  for (int mf = 0; mf < 4; ++mf)
#pragma unroll
    for (int nf = 0; nf < 4; ++nf)
#pragma unroll
      for (int r = 0; r < 4; ++r) {
        const int n = n0w + mf * 16 + lg * 4 + r;
        ub[(size_t)n * DM + h * 64 + nf * 16 + lr] = (__bf16)acc[mf][nf][r];
      }
}

// ---------------------------------------------------------------------------
// K4: out[b] = Q[b] @ Ut[b]^T + bias.  Batched: 4 x (M=4096, N=1024, K=1024).
// BM=BN=128, BK=64. B (Ut, bf16 [n][k]) staged via global_load_lds w16 with
// pre-swizzled source; A (Q, f32) reg-staged -> bf16 -> swizzled ds_write_b128,
// with next-tile A-loads issued inside the compute region (overlap MFMA).
// grid = 4*8*32 = 1024; mblk inner so consecutive blocks share the Ut panel.
// ---------------------------------------------------------------------------
__global__ __launch_bounds__(256)
void k4_out_gemm(const float* __restrict__ Qg,
                 const __bf16* __restrict__ Ut,
                 const float* __restrict__ biasg,
                 float* __restrict__ outg) {
  __shared__ __align__(16) __bf16 Alds[128 * 64];
  __shared__ __align__(16) __bf16 Blds[128 * 64];
  const int bid = blockIdx.x;
  const int b = bid >> 8, rem = bid & 255;
  const int nblk = rem >> 5, mblk = rem & 31;
  const int m0 = mblk * 128, n0 = nblk * 128;
  const int t = threadIdx.x, wid = t >> 6, l = t & 63, lr = l & 15, lg = l >> 4;
  const int wr = wid >> 1, wc = wid & 1;
  const float* Qb = Qg + (size_t)b * S_ * DM;
  const __bf16* Ub = Ut + ((size_t)b << 20);
  f32x4 acc[4][4] = {};

  const int srow = (t >> 3), sc = t & 7;          // staging row/chunk base (it=0)
  bf16x8 aregs[4];

  // load A-regs for kt=0
#pragma unroll
  for (int it = 0; it < 4; ++it) {
    const int row = it * 32 + srow;
    const float* qp = Qb + (size_t)(m0 + row) * DM + sc * 8;
    f32x4 lo = *reinterpret_cast<const f32x4*>(qp);
    f32x4 hi = *reinterpret_cast<const f32x4*>(qp + 4);
#pragma unroll
    for (int j = 0; j < 4; ++j) { aregs[it][j] = (__bf16)lo[j]; aregs[it][4 + j] = (__bf16)hi[j]; }
  }

  for (int kt = 0; kt < 16; ++kt) {
    const int k0 = kt * 64;
    // stage B via global_load_lds (pre-swizzled source, linear LDS dest)
#pragma unroll
    for (int it = 0; it < 4; ++it) {
      const int row = it * 32 + srow;
      const int gc = sc ^ (row & 7);
      gload_lds16((const void*)(Ub + (size_t)(n0 + row) * DM + k0 + gc * 8),
                  (void*)((char*)Blds + (it * 256 + wid * 64) * 16));
    }
    // stage A: swizzled ds_write of held regs
#pragma unroll
    for (int it = 0; it < 4; ++it) {
      const int row = it * 32 + srow;
      const int ch = sc ^ (row & 7);
      *reinterpret_cast<bf16x8*>((char*)Alds + row * 128 + ch * 16) = aregs[it];
    }
    __syncthreads();
    // prefetch A-regs for next tile (issued in compute region -> overlaps MFMA)
    if (kt < 15) {
#pragma unroll
      for (int it = 0; it < 4; ++it) {
        const int row = it * 32 + srow;
        const float* qp = Qb + (size_t)(m0 + row) * DM + (k0 + 64) + sc * 8;
        f32x4 lo = *reinterpret_cast<const f32x4*>(qp);
        f32x4 hi = *reinterpret_cast<const f32x4*>(qp + 4);
#pragma unroll
        for (int j = 0; j < 4; ++j) { aregs[it][j] = (__bf16)lo[j]; aregs[it][4 + j] = (__bf16)hi[j]; }
      }
    }
#pragma unroll
    for (int ks = 0; ks < 2; ++ks) {
      bf16x8 af[4], bfr[4];
#pragma unroll
      for (int mt = 0; mt < 4; ++mt) {
        const int row = wr * 64 + mt * 16 + lr;
        const int ch = (ks * 4 + lg) ^ (row & 7);
        af[mt] = *reinterpret_cast<const bf16x8*>((const char*)Alds + row * 128 + ch * 16);
      }
#pragma unroll
      for (int nt = 0; nt < 4; ++nt) {
        const int row = wc * 64 + nt * 16 + lr;
        const int ch = (ks * 4 + lg) ^ (row & 7);
        bfr[nt] = *reinterpret_cast<const bf16x8*>((const char*)Blds + row * 128 + ch * 16);
      }
#pragma unroll
      for (int mt = 0; mt < 4; ++mt)
#pragma unroll
        for (int nt = 0; nt < 4; ++nt)
          acc[mt][nt] = MFMA16(af[mt], bfr[nt], acc[mt][nt]);
    }
    __syncthreads();
  }

  // epilogue: + f32 bias, f32 store
#pragma unroll
  for (int nt = 0; nt < 4; ++nt) {
    const int colg = n0 + wc * 64 + nt * 16 + lr;
    const float bv = biasg[colg];
#pragma unroll
    for (int mt = 0; mt < 4; ++mt)
#pragma unroll
      for (int r = 0; r < 4; ++r) {
        const int rowg = m0 + wr * 64 + mt * 16 + lg * 4 + r;
        outg[((size_t)b * S_ + rowg) * DM + colg] = acc[mt][nt][r] + bv;
      }
  }
}

extern "C" void kernel_launch(void* const* d_in, const int* in_sizes, int n_in,
                              void* d_out, int out_size, void* d_ws, size_t ws_size,
                              hipStream_t stream) {
  const float* Q = (const float*)d_in[0];
  const float* K = (const float*)d_in[1];
  const float* V = (const float*)d_in[2];
  const float* W = (const float*)d_in[3];
  const float* bias = (const float*)d_in[4];
  float* out = (float*)d_out;

  char* ws = (char*)d_ws;
  float* partial = (float*)ws;                       // 16 MiB
  __bf16* kvt = (__bf16*)(ws + 16777216);            // 512 KiB
  __bf16* Ut  = (__bf16*)(ws + 16777216 + 524288);   // 8 MiB

  hipLaunchKernelGGL(k1_kv_partial, dim3(SPLIT * BH), dim3(256), 0, stream, K, V, partial);
  hipLaunchKernelGGL(k2_kv_reduce, dim3(BH * 4), dim3(256), 0, stream, partial, kvt);
  hipLaunchKernelGGL(k25_u, dim3(BH * 4), dim3(256), 0, stream, W, kvt, Ut);
  hipLaunchKernelGGL(k4_out_gemm, dim3(1024), dim3(256), 0, stream, Q, Ut, bias, out);
}

// Round 4
// 121.288 us; speedup vs baseline: 1.1071x; 1.1071x over previous
//
#include <hip/hip_runtime.h>
#include <hip/hip_bf16.h>

#define B_ 4
#define S_ 4096
#define DM 1024
#define H_ 16
#define HD 64
#define BH (B_*H_)
#define SPLIT 16
#define CHUNK (S_/SPLIT)   // 256

typedef __attribute__((ext_vector_type(8))) __bf16 bf16x8;
typedef __attribute__((ext_vector_type(4))) __bf16 bf16x4;
typedef __attribute__((ext_vector_type(4))) float f32x4;

#define MFMA16(a,b,c) __builtin_amdgcn_mfma_f32_16x16x32_bf16((a),(b),(c),0,0,0)

__device__ __forceinline__ void gload_lds16(const void* g, void* l) {
  __builtin_amdgcn_global_load_lds(
      (const __attribute__((address_space(1))) void*)g,
      (__attribute__((address_space(3))) void*)l, 16, 0, 0);
}

// ---------------------------------------------------------------------------
// K1: partial KV[split][bh][d][e] = sum_{s in chunk} K[s][d]*V[s][e]  (f32)
//     + fused Q f32->bf16 conversion of the SAME [b, s-chunk, head] tile.
// grid = SPLIT*BH = 1024 blocks, 256 threads.
// ---------------------------------------------------------------------------
__global__ __launch_bounds__(256)
void k1_kv_partial(const float* __restrict__ Qg,
                   const float* __restrict__ Kg,
                   const float* __restrict__ Vg,
                   float* __restrict__ partial,
                   __bf16* __restrict__ Qb) {
  constexpr int LDP = 264;
  __shared__ __align__(16) __bf16 Kt[64 * LDP];
  __shared__ __align__(16) __bf16 Vt[64 * LDP];
  const int bid = blockIdx.x;
  const int split = bid >> 6;
  const int bh = bid & (BH - 1);
  const int b = bh >> 4, h = bh & 15;
  const int s0 = split * CHUNK;
  const int t = threadIdx.x;
  const size_t base = ((size_t)b * S_ + s0) * DM + h * HD;
  const float* Kbase = Kg + base;
  const float* Vbase = Vg + base;
  const float* Qbase = Qg + base;
  __bf16* Qbb = Qb + base;
  const int c = t & 15, sr = t >> 4;
  const int d0 = c * 4;
#pragma unroll
  for (int it = 0; it < 16; ++it) {
    const int s = it * 16 + sr;
    f32x4 kv = *reinterpret_cast<const f32x4*>(Kbase + (size_t)s * DM + d0);
    f32x4 vv = *reinterpret_cast<const f32x4*>(Vbase + (size_t)s * DM + d0);
    f32x4 qv = *reinterpret_cast<const f32x4*>(Qbase + (size_t)s * DM + d0);
    bf16x4 qo;
#pragma unroll
    for (int j = 0; j < 4; ++j) {
      Kt[(d0 + j) * LDP + s] = (__bf16)kv[j];
      Vt[(d0 + j) * LDP + s] = (__bf16)vv[j];
      qo[j] = (__bf16)qv[j];
    }
    *reinterpret_cast<bf16x4*>(Qbb + (size_t)s * DM + d0) = qo;
  }
  __syncthreads();
  const int w = t >> 6, l = t & 63, lr = l & 15, lg = l >> 4;
  f32x4 acc[4] = {};
#pragma unroll
  for (int ks = 0; ks < 8; ++ks) {
    bf16x8 a = *reinterpret_cast<const bf16x8*>(&Kt[(w * 16 + lr) * LDP + ks * 32 + lg * 8]);
#pragma unroll
    for (int n = 0; n < 4; ++n) {
      bf16x8 bb = *reinterpret_cast<const bf16x8*>(&Vt[(n * 16 + lr) * LDP + ks * 32 + lg * 8]);
      acc[n] = MFMA16(a, bb, acc[n]);
    }
  }
  float* dst = partial + ((size_t)(split * BH + bh) << 12);
#pragma unroll
  for (int n = 0; n < 4; ++n)
#pragma unroll
    for (int r = 0; r < 4; ++r) {
      const int d = w * 16 + lg * 4 + r;
      const int e = n * 16 + lr;
      dst[d * 64 + e] = acc[n][r];
    }
}

// ---------------------------------------------------------------------------
// K2: reduce 16 partials -> kvt[bh][d][e] bf16.  grid = BH*4 = 256 blocks.
// ---------------------------------------------------------------------------
__global__ __launch_bounds__(256)
void k2_kv_reduce(const float* __restrict__ partial,
                  __bf16* __restrict__ kvt) {
  const int bid = blockIdx.x;
  const int bh = bid >> 2, q = bid & 3;
  const int t = threadIdx.x;
#pragma unroll
  for (int i = 0; i < 4; ++i) {
    const int idx = q * 1024 + i * 256 + t;   // d*64+e
    float s = 0.f;
#pragma unroll
    for (int sp = 0; sp < SPLIT; ++sp)
      s += partial[((size_t)(sp * BH + bh) << 12) + idx];
    kvt[((size_t)bh << 12) + idx] = (__bf16)s;
  }
}

// ---------------------------------------------------------------------------
// K2.5: Ut[b][n][h*64+d] = sum_e W[n][h*64+e] * KV[bh][d][e]   (bf16 out)
// grid = BH*4 = 256 blocks.  (unchanged, verified)
// ---------------------------------------------------------------------------
__global__ __launch_bounds__(256)
void k25_u(const float* __restrict__ Wg,
           const __bf16* __restrict__ kvt,
           __bf16* __restrict__ Ut) {
  const int bid = blockIdx.x;
  const int bh = bid >> 2, nblk = bid & 3;
  const int b = bh >> 4, h = bh & 15;
  const int t = threadIdx.x, w = t >> 6, l = t & 63, lr = l & 15, lg = l >> 4;
  const int n0w = nblk * 256 + w * 64;
  const __bf16* kvb = kvt + ((size_t)bh << 12);
  f32x4 acc[4][4] = {};
#pragma unroll
  for (int ks = 0; ks < 2; ++ks) {
    bf16x8 bfr[4];
#pragma unroll
    for (int nf = 0; nf < 4; ++nf)
      bfr[nf] = *reinterpret_cast<const bf16x8*>(kvb + (nf * 16 + lr) * 64 + ks * 32 + lg * 8);
#pragma unroll
    for (int mf = 0; mf < 4; ++mf) {
      const int n = n0w + mf * 16 + lr;
      const float* wp = Wg + (size_t)n * DM + h * 64 + ks * 32 + lg * 8;
      f32x4 w0 = *reinterpret_cast<const f32x4*>(wp);
      f32x4 w1 = *reinterpret_cast<const f32x4*>(wp + 4);
      bf16x8 af;
#pragma unroll
      for (int j = 0; j < 4; ++j) { af[j] = (__bf16)w0[j]; af[4 + j] = (__bf16)w1[j]; }
#pragma unroll
      for (int nf = 0; nf < 4; ++nf)
        acc[mf][nf] = MFMA16(af, bfr[nf], acc[mf][nf]);
    }
  }
  __bf16* ub = Ut + ((size_t)b << 20);
#pragma unroll
  for (int mf = 0; mf < 4; ++mf)
#pragma unroll
    for (int nf = 0; nf < 4; ++nf)
#pragma unroll
      for (int r = 0; r < 4; ++r) {
        const int n = n0w + mf * 16 + lg * 4 + r;
        ub[(size_t)n * DM + h * 64 + nf * 16 + lr] = (__bf16)acc[mf][nf][r];
      }
}

// ---------------------------------------------------------------------------
// K4: out[b] = Qb[b] @ Ut[b]^T + bias.  4 x (M=4096, N=1024, K=1024).
// Round-2-proven structure: BOTH operands bf16 via global_load_lds w16,
// pre-swizzled global source + swizzled ds_read_b128 (conflict-free).
// grid = 4*8*32 = 1024; mblk inner (consecutive blocks share the Ut panel).
// ---------------------------------------------------------------------------
__global__ __launch_bounds__(256)
void k4_out_gemm(const __bf16* __restrict__ Qb,
                 const __bf16* __restrict__ Ut,
                 const float* __restrict__ biasg,
                 float* __restrict__ outg) {
  __shared__ __align__(16) __bf16 Alds[128 * 64];
  __shared__ __align__(16) __bf16 Blds[128 * 64];
  const int bid = blockIdx.x;
  const int b = bid >> 8, rem = bid & 255;
  const int nblk = rem >> 5, mblk = rem & 31;
  const int m0 = mblk * 128, n0 = nblk * 128;
  const int t = threadIdx.x, wid = t >> 6, l = t & 63, lr = l & 15, lg = l >> 4;
  const int wr = wid >> 1, wc = wid & 1;
  const __bf16* Ab = Qb + (size_t)b * S_ * DM;
  const __bf16* Bb = Ut + ((size_t)b << 20);
  f32x4 acc[4][4] = {};

  for (int kt = 0; kt < 16; ++kt) {
    const int k0 = kt * 64;
#pragma unroll
    for (int it = 0; it < 4; ++it) {
      const int idx = it * 256 + t;          // (row, 16B-chunk)
      const int row = idx >> 3, c = idx & 7;
      const int gc = c ^ (row & 7);          // pre-swizzled global source
      gload_lds16((const void*)(Ab + (size_t)(m0 + row) * DM + k0 + gc * 8),
                  (void*)((char*)Alds + (it * 256 + wid * 64) * 16));
      gload_lds16((const void*)(Bb + (size_t)(n0 + row) * DM + k0 + gc * 8),
                  (void*)((char*)Blds + (it * 256 + wid * 64) * 16));
    }
    __syncthreads();
#pragma unroll
    for (int ks = 0; ks < 2; ++ks) {
      bf16x8 af[4], bfr[4];
#pragma unroll
      for (int mt = 0; mt < 4; ++mt) {
        const int row = wr * 64 + mt * 16 + lr;
        const int ch = (ks * 4 + lg) ^ (row & 7);
        af[mt] = *reinterpret_cast<const bf16x8*>((const char*)Alds + row * 128 + ch * 16);
      }
#pragma unroll
      for (int nt = 0; nt < 4; ++nt) {
        const int row = wc * 64 + nt * 16 + lr;
        const int ch = (ks * 4 + lg) ^ (row & 7);
        bfr[nt] = *reinterpret_cast<const bf16x8*>((const char*)Blds + row * 128 + ch * 16);
      }
#pragma unroll
      for (int mt = 0; mt < 4; ++mt)
#pragma unroll
        for (int nt = 0; nt < 4; ++nt)
          acc[mt][nt] = MFMA16(af[mt], bfr[nt], acc[mt][nt]);
    }
    __syncthreads();
  }

  // epilogue: + f32 bias, f32 store
#pragma unroll
  for (int nt = 0; nt < 4; ++nt) {
    const int colg = n0 + wc * 64 + nt * 16 + lr;
    const float bv = biasg[colg];
#pragma unroll
    for (int mt = 0; mt < 4; ++mt)
#pragma unroll
      for (int r = 0; r < 4; ++r) {
        const int rowg = m0 + wr * 64 + mt * 16 + lg * 4 + r;
        outg[((size_t)b * S_ + rowg) * DM + colg] = acc[mt][nt][r] + bv;
      }
  }
}

extern "C" void kernel_launch(void* const* d_in, const int* in_sizes, int n_in,
                              void* d_out, int out_size, void* d_ws, size_t ws_size,
                              hipStream_t stream) {
  const float* Q = (const float*)d_in[0];
  const float* K = (const float*)d_in[1];
  const float* V = (const float*)d_in[2];
  const float* W = (const float*)d_in[3];
  const float* bias = (const float*)d_in[4];
  float* out = (float*)d_out;

  char* ws = (char*)d_ws;
  float* partial = (float*)ws;                        // 16 MiB @ 0
  __bf16* kvt = (__bf16*)(ws + (16u << 20));          // 512 KiB
  __bf16* Ut  = (__bf16*)(ws + (16u << 20) + (512u << 10));   // 8 MiB
  __bf16* Qb  = (__bf16*)(ws + (25u << 20));          // 32 MiB

  hipLaunchKernelGGL(k1_kv_partial, dim3(SPLIT * BH), dim3(256), 0, stream, Q, K, V, partial, Qb);
  hipLaunchKernelGGL(k2_kv_reduce, dim3(BH * 4), dim3(256), 0, stream, partial, kvt);
  hipLaunchKernelGGL(k25_u, dim3(BH * 4), dim3(256), 0, stream, W, kvt, Ut);
  hipLaunchKernelGGL(k4_out_gemm, dim3(1024), dim3(256), 0, stream, Qb, Ut, bias, out);
}